// Round 12
// baseline (23.475 us; speedup 1.0000x reference)
//
#include <hip/hip_runtime.h>

typedef _Float16 f16;
typedef _Float16 f16x8 __attribute__((ext_vector_type(8)));
typedef float f32x4 __attribute__((ext_vector_type(4)));

#define MFMA16(a, b, c) __builtin_amdgcn_mfma_f32_16x16x32_f16((a), (b), (c), 0, 0, 0)

// ---------------- LDS (u16 units) ----------------
// E region overlaid by GT after BC; EP region overlaid by G2F; EA region overlaid by H.
#define E_HI   0        // E [32][72]
#define E_LO   2304
#define GT_HI  0        // G transposed [64][36] (overlays E after BC)
#define GT_LO  2304
#define EA_HI  4608     // EA [32][72] -> H reuse
#define EA_LO  6912
#define EP_HI  9216     // EP [32][72]
#define EP_LO  11520
#define G2F_O  9216     // g2 [32][68] f32 (overlays EP after BC)
#define KB_HI  13824    // K [32][72]
#define KB_LO  16128
#define QB_HI  18432    // Q [32][72]
#define QB_LO  20736
#define AAN_HI 23040    // AA natural [32][72]
#define AAN_LO 25344
#define DDN_HI 27648    // dDiff natural [32][72]
#define DDN_LO 29952
#define WM_HI  32256    // softmax w [32][40]
#define WM_LO  33536
#define WDIAG  34816    // float[32]
#define SMTOT  34880    // 69760 B -> 2 blocks/CU

__device__ __forceinline__ void split1(float v, ushort& h, ushort& lo) {
    f16 hf = (f16)v;
    float r = v - (float)hf;
    f16 lf = (f16)r;
    union { f16 f; ushort u; } a, b;
    a.f = hf; b.f = lf;
    h = a.u; lo = b.u;
}
__device__ __forceinline__ void split4(f32x4 v, ushort4& h, ushort4& l) {
    split1(v[0], h.x, l.x);
    split1(v[1], h.y, l.y);
    split1(v[2], h.z, l.z);
    split1(v[3], h.w, l.w);
}
__device__ __forceinline__ void mk8(float4 a, float4 b, f16x8& hi, f16x8& lo) {
    float v[8] = {a.x, a.y, a.z, a.w, b.x, b.y, b.z, b.w};
    #pragma unroll
    for (int j = 0; j < 8; ++j) {
        f16 h = (f16)v[j];
        hi[j] = h;
        lo[j] = (f16)(v[j] - (float)h);
    }
}
// raw fp32 fragment: 8 consecutive floats -> hi/lo f16x8
__device__ __forceinline__ void ldraw(const float* p, f16x8& h, f16x8& l) {
    float4 a = *(const float4*)p;
    float4 b = *(const float4*)(p + 4);
    mk8(a, b, h, l);
}
__device__ __forceinline__ f16x8 ldf(const ushort* sm, int off) {
    return *(const f16x8*)(sm + off);
}
__device__ __forceinline__ float fast_tanh(float x) {
    float xc = fminf(fmaxf(x, -9.0f), 9.0f);
    float e = __expf(2.0f * xc);
    return (e - 1.0f) * __builtin_amdgcn_rcpf(e + 1.0f);
}

__global__ void __launch_bounds__(256, 2)
critic_mfma(const float* __restrict__ states, const float* __restrict__ policies,
            const float* __restrict__ actions, const float* __restrict__ b_obs,
            const float* __restrict__ b_oa,
            const float* __restrict__ W_obs, const float* __restrict__ W_oa,
            const float* __restrict__ W_key, const float* __restrict__ W_query,
            const float* __restrict__ W_av,  const float* __restrict__ W_f1,
            const float* __restrict__ W_f2,
            float* __restrict__ out_value,   // [B,32,16]
            float* __restrict__ out_weight)  // [B,32,32]
{
    __shared__ ushort sm[SMTOT];
    const int b = blockIdx.x;
    const int t = threadIdx.x;
    const int wv = t >> 6, l = t & 63;
    const int lr = l & 15;        // lane row/col within 16-tile
    const int lg = l >> 4;        // k-group / output reg-quad
    const int ft = wv;            // feature tile (M dim) 0..3
    const int row = ft * 16 + lr;        // weight row this lane owns
    const int f0 = ft * 16 + lg * 4;     // output feature quad base

    // ---- states B-fragments straight from global (all waves same addrs -> L1 broadcast) ----
    f16x8 sxh[2][4], sxl[2][4];
    #pragma unroll
    for (int at = 0; at < 2; ++at)
        #pragma unroll
        for (int c = 0; c < 4; ++c)
            ldraw(states + (size_t)b * 4096 + (at * 16 + lr) * 128 + c * 32 + lg * 8,
                  sxh[at][c], sxl[at][c]);

    // ---- phase-A weight fragments ----
    f16x8 wObsH[4], wObsL[4], wOaH[4], wOaL[4];
    #pragma unroll
    for (int c = 0; c < 4; ++c) {
        ldraw(W_obs + row * 128 + c * 32 + lg * 8, wObsH[c], wObsL[c]);
        ldraw(W_oa + row * 144 + c * 32 + lg * 8, wOaH[c], wOaL[c]);
    }
    f16x8 wTailH, wTailL;
    {
        float4 t0 = make_float4(0.f, 0.f, 0.f, 0.f), t1 = t0;
        if (lg < 2) {
            t0 = *(const float4*)(W_oa + row * 144 + 128 + lg * 8);
            t1 = *(const float4*)(W_oa + row * 144 + 132 + lg * 8);
        }
        mk8(t0, t1, wTailH, wTailL);
    }

    // ---- act/pol tail B-fragments (k>=16 zero) ----
    f16x8 actH[2], actL[2], polH[2], polL[2];
    #pragma unroll
    for (int at = 0; at < 2; ++at) {
        float4 a0v = make_float4(0.f, 0.f, 0.f, 0.f), a1v = a0v, p0v = a0v, p1v = a0v;
        if (lg < 2) {
            size_t base = (size_t)b * 512 + (at * 16 + lr) * 16 + lg * 8;
            a0v = *(const float4*)(actions + base);
            a1v = *(const float4*)(actions + base + 4);
            p0v = *(const float4*)(policies + base);
            p1v = *(const float4*)(policies + base + 4);
        }
        mk8(a0v, a1v, actH[at], actL[at]);
        mk8(p0v, p1v, polH[at], polL[at]);
    }

    const f32x4 Z = {0.f, 0.f, 0.f, 0.f};

    // ================= phase A: E = relu(S@WobsT+b); EA/EP = relu(S@WoaT + tail + b) =================
    f32x4 accE[2] = {Z, Z}, accP[2] = {Z, Z};
    #pragma unroll
    for (int c = 0; c < 4; ++c) {
        #pragma unroll
        for (int at = 0; at < 2; ++at) {
            accE[at] = MFMA16(wObsH[c], sxh[at][c], accE[at]);
            accE[at] = MFMA16(wObsH[c], sxl[at][c], accE[at]);
            accE[at] = MFMA16(wObsL[c], sxh[at][c], accE[at]);
            accP[at] = MFMA16(wOaH[c], sxh[at][c], accP[at]);
            accP[at] = MFMA16(wOaH[c], sxl[at][c], accP[at]);
            accP[at] = MFMA16(wOaL[c], sxh[at][c], accP[at]);
        }
    }
    f32x4 accEA[2], accEP[2];
    #pragma unroll
    for (int at = 0; at < 2; ++at) {
        accEA[at] = accP[at]; accEP[at] = accP[at];
        accEA[at] = MFMA16(wTailH, actH[at], accEA[at]);
        accEA[at] = MFMA16(wTailH, actL[at], accEA[at]);
        accEA[at] = MFMA16(wTailL, actH[at], accEA[at]);
        accEP[at] = MFMA16(wTailH, polH[at], accEP[at]);
        accEP[at] = MFMA16(wTailH, polL[at], accEP[at]);
        accEP[at] = MFMA16(wTailL, polH[at], accEP[at]);
    }

    // prefetch phase-BC weights
    f16x8 wKH[2], wKL[2], wQH[2], wQL[2], wVH[2], wVL[2];
    #pragma unroll
    for (int c = 0; c < 2; ++c) {
        ldraw(W_key + row * 64 + c * 32 + lg * 8, wKH[c], wKL[c]);
        ldraw(W_query + row * 64 + c * 32 + lg * 8, wQH[c], wQL[c]);
        ldraw(W_av + row * 64 + c * 32 + lg * 8, wVH[c], wVL[c]);
    }

    {
        float4 bo = *(const float4*)&b_obs[f0];
        float4 ba = *(const float4*)&b_oa[f0];
        #pragma unroll
        for (int at = 0; at < 2; ++at) {
            int agent = at * 16 + lr;
            f32x4 e, ea, ep;
            e[0] = fmaxf(accE[at][0] + bo.x, 0.f);  e[1] = fmaxf(accE[at][1] + bo.y, 0.f);
            e[2] = fmaxf(accE[at][2] + bo.z, 0.f);  e[3] = fmaxf(accE[at][3] + bo.w, 0.f);
            ea[0] = fmaxf(accEA[at][0] + ba.x, 0.f); ea[1] = fmaxf(accEA[at][1] + ba.y, 0.f);
            ea[2] = fmaxf(accEA[at][2] + ba.z, 0.f); ea[3] = fmaxf(accEA[at][3] + ba.w, 0.f);
            ep[0] = fmaxf(accEP[at][0] + ba.x, 0.f); ep[1] = fmaxf(accEP[at][1] + ba.y, 0.f);
            ep[2] = fmaxf(accEP[at][2] + ba.z, 0.f); ep[3] = fmaxf(accEP[at][3] + ba.w, 0.f);
            ushort4 h, lo;
            split4(e, h, lo);
            *(ushort4*)(sm + E_HI + agent * 72 + f0) = h;
            *(ushort4*)(sm + E_LO + agent * 72 + f0) = lo;
            split4(ea, h, lo);
            *(ushort4*)(sm + EA_HI + agent * 72 + f0) = h;
            *(ushort4*)(sm + EA_LO + agent * 72 + f0) = lo;
            split4(ep, h, lo);
            *(ushort4*)(sm + EP_HI + agent * 72 + f0) = h;
            *(ushort4*)(sm + EP_LO + agent * 72 + f0) = lo;
        }
    }
    __syncthreads();   // barrier 1

    // ================= phase BC: K=E@WkT, Q=E@WqT, AA/AP=tanh(EA/EP@WavT) =================
    {
        f32x4 aK[2] = {Z, Z}, aQ[2] = {Z, Z}, aA[2] = {Z, Z}, aP[2] = {Z, Z};
        #pragma unroll
        for (int c = 0; c < 2; ++c) {
            #pragma unroll
            for (int at = 0; at < 2; ++at) {
                int ao = (at * 16 + lr) * 72 + c * 32 + lg * 8;
                f16x8 eh = ldf(sm, E_HI + ao),  el = ldf(sm, E_LO + ao);
                f16x8 xh = ldf(sm, EA_HI + ao), xl = ldf(sm, EA_LO + ao);
                f16x8 yh = ldf(sm, EP_HI + ao), yl = ldf(sm, EP_LO + ao);
                aK[at] = MFMA16(wKH[c], eh, aK[at]);
                aK[at] = MFMA16(wKH[c], el, aK[at]);
                aK[at] = MFMA16(wKL[c], eh, aK[at]);
                aQ[at] = MFMA16(wQH[c], eh, aQ[at]);
                aQ[at] = MFMA16(wQH[c], el, aQ[at]);
                aQ[at] = MFMA16(wQL[c], eh, aQ[at]);
                aA[at] = MFMA16(wVH[c], xh, aA[at]);
                aA[at] = MFMA16(wVH[c], xl, aA[at]);
                aA[at] = MFMA16(wVL[c], xh, aA[at]);
                aP[at] = MFMA16(wVH[c], yh, aP[at]);
                aP[at] = MFMA16(wVH[c], yl, aP[at]);
                aP[at] = MFMA16(wVL[c], yh, aP[at]);
            }
        }
        #pragma unroll
        for (int at = 0; at < 2; ++at) {
            int agent = at * 16 + lr;
            ushort4 h, lo;
            split4(aK[at], h, lo);
            *(ushort4*)(sm + KB_HI + agent * 72 + f0) = h;
            *(ushort4*)(sm + KB_LO + agent * 72 + f0) = lo;
            split4(aQ[at], h, lo);
            *(ushort4*)(sm + QB_HI + agent * 72 + f0) = h;
            *(ushort4*)(sm + QB_LO + agent * 72 + f0) = lo;
            f32x4 ta, tp, dd;
            #pragma unroll
            for (int r = 0; r < 4; ++r) {
                ta[r] = fast_tanh(aA[at][r]);
                tp[r] = fast_tanh(aP[at][r]);
                dd[r] = tp[r] - ta[r];
            }
            split4(ta, h, lo);
            *(ushort4*)(sm + AAN_HI + agent * 72 + f0) = h;   // AA natural
            *(ushort4*)(sm + AAN_LO + agent * 72 + f0) = lo;
            split4(dd, h, lo);
            *(ushort4*)(sm + DDN_HI + agent * 72 + f0) = h;   // dDiff natural
            *(ushort4*)(sm + DDN_LO + agent * 72 + f0) = lo;
        }
    }

    // prefetch: waves 0,1 -> Wf2 (phase F); waves 2,3 -> their Wf1 rows (phase G)
    f16x8 wF2H[2], wF2L[2];
    f16x8 wG1H[2][2], wG1L[2][2];   // [gi][c]
    if (wv < 2) {
        #pragma unroll
        for (int c = 0; c < 2; ++c)
            ldraw(W_f2 + lr * 64 + c * 32 + lg * 8, wF2H[c], wF2L[c]);
    } else {
        int w = wv - 2;
        #pragma unroll
        for (int gi = 0; gi < 2; ++gi) {
            int gft = w * 2 + gi;
            #pragma unroll
            for (int c = 0; c < 2; ++c)
                ldraw(W_f1 + (gft * 16 + lr) * 64 + c * 32 + lg * 8, wG1H[gi][c], wG1L[gi][c]);
        }
    }
    __syncthreads();   // barrier 2

    // ================= waves 0,1: score+softmax | waves 2,3: G = AA@Wf1T, g2 = dDiff@Wf1T =================
    if (wv < 2) {
        int jt = wv;
        f16x8 kh[2], kl[2];
        #pragma unroll
        for (int c = 0; c < 2; ++c) {
            int ko = (jt * 16 + lr) * 72 + c * 32 + lg * 8;
            kh[c] = ldf(sm, KB_HI + ko);
            kl[c] = ldf(sm, KB_LO + ko);
        }
        f32x4 s[2] = {Z, Z};
        #pragma unroll
        for (int c = 0; c < 2; ++c) {
            #pragma unroll
            for (int it = 0; it < 2; ++it) {
                int qo = (it * 16 + lr) * 72 + c * 32 + lg * 8;
                f16x8 qh = ldf(sm, QB_HI + qo), ql = ldf(sm, QB_LO + qo);
                s[it] = MFMA16(kh[c], qh, s[it]);
                s[it] = MFMA16(kh[c], ql, s[it]);
                s[it] = MFMA16(kl[c], qh, s[it]);
            }
        }
        float* wdiag = (float*)(sm + WDIAG);
        #pragma unroll
        for (int r = 0; r < 4; ++r) {
            int j = jt * 16 + lg * 4 + r;
            float v0 = s[0][r] * 0.125f, v1 = s[1][r] * 0.125f;
            float m = fmaxf(v0, v1);
            #pragma unroll
            for (int off = 1; off < 16; off <<= 1)
                m = fmaxf(m, __shfl_xor(m, off, 16));
            float e0 = __expf(v0 - m), e1 = __expf(v1 - m);
            float su = e0 + e1;
            #pragma unroll
            for (int off = 1; off < 16; off <<= 1)
                su += __shfl_xor(su, off, 16);
            float inv = 1.0f / su;
            e0 *= inv; e1 *= inv;
            out_weight[(size_t)b * 1024 + j * 32 + lr] = e0;
            out_weight[(size_t)b * 1024 + j * 32 + 16 + lr] = e1;
            ushort hh, ll;
            split1(e0, hh, ll);
            sm[WM_HI + j * 40 + lr] = hh;
            sm[WM_LO + j * 40 + lr] = ll;
            split1(e1, hh, ll);
            sm[WM_HI + j * 40 + 16 + lr] = hh;
            sm[WM_LO + j * 40 + 16 + lr] = ll;
            if (lr == lg * 4 + r) wdiag[j] = jt ? e1 : e0;
        }
    } else {
        int w = wv - 2;
        float* G2Ff = (float*)(sm + G2F_O);
        #pragma unroll
        for (int gi = 0; gi < 2; ++gi) {
            int gft = w * 2 + gi;
            #pragma unroll
            for (int it = 0; it < 2; ++it) {
                f32x4 aG = Z, aG2 = Z;
                #pragma unroll
                for (int c = 0; c < 2; ++c) {
                    int ao = (it * 16 + lr) * 72 + c * 32 + lg * 8;
                    f16x8 anh = ldf(sm, AAN_HI + ao), anl = ldf(sm, AAN_LO + ao);
                    f16x8 ddh = ldf(sm, DDN_HI + ao), ddl = ldf(sm, DDN_LO + ao);
                    aG  = MFMA16(wG1H[gi][c], anh, aG);
                    aG  = MFMA16(wG1H[gi][c], anl, aG);
                    aG  = MFMA16(wG1L[gi][c], anh, aG);
                    aG2 = MFMA16(wG1H[gi][c], ddh, aG2);
                    aG2 = MFMA16(wG1H[gi][c], ddl, aG2);
                    aG2 = MFMA16(wG1L[gi][c], ddh, aG2);
                }
                #pragma unroll
                for (int r = 0; r < 4; ++r) {
                    int f = gft * 16 + lg * 4 + r;
                    int i = it * 16 + lr;
                    ushort hh, ll;
                    split1(aG[r], hh, ll);
                    sm[GT_HI + f * 36 + i] = hh;     // G transposed (overlays dead E)
                    sm[GT_LO + f * 36 + i] = ll;
                    G2Ff[i * 68 + f] = aG2[r];       // g2 f32 natural (overlays dead EP)
                }
            }
        }
    }
    __syncthreads();   // barrier 3

    // ================= phase D': H = lrelu((WM@G + wd*g2)/32) =================
    {
        int fo = (ft * 16 + lr) * 36 + lg * 8;
        f16x8 gh = ldf(sm, GT_HI + fo);
        f16x8 gl = ldf(sm, GT_LO + fo);
        const float* wdiag = (const float*)(sm + WDIAG);
        const float* G2Ff = (const float*)(sm + G2F_O);
        #pragma unroll
        for (int jt = 0; jt < 2; ++jt) {
            int j = jt * 16 + lr;
            f16x8 wh = ldf(sm, WM_HI + j * 40 + lg * 8);
            f16x8 wl = ldf(sm, WM_LO + j * 40 + lg * 8);
            f32x4 acc = Z;
            acc = MFMA16(gh, wh, acc);
            acc = MFMA16(gh, wl, acc);
            acc = MFMA16(gl, wh, acc);
            float wd = wdiag[j];
            float4 g2v = *(const float4*)(G2Ff + j * 68 + f0);
            f32x4 hv;
            hv[0] = (acc[0] + wd * g2v.x) * 0.03125f;
            hv[1] = (acc[1] + wd * g2v.y) * 0.03125f;
            hv[2] = (acc[2] + wd * g2v.z) * 0.03125f;
            hv[3] = (acc[3] + wd * g2v.w) * 0.03125f;
            #pragma unroll
            for (int r = 0; r < 4; ++r)
                hv[r] = fmaxf(hv[r], 0.01f * hv[r]);
            ushort4 h, lo;
            split4(hv, h, lo);
            *(ushort4*)(sm + EA_HI + j * 72 + f0) = h;   // H overwrites EA (dead)
            *(ushort4*)(sm + EA_LO + j * 72 + f0) = lo;
        }
    }
    __syncthreads();   // barrier 4

    // ================= phase F (waves 0,1): value = H @ Wf2T =================
    if (wv < 2) {
        int jt = wv;
        f32x4 acc = Z;
        #pragma unroll
        for (int c = 0; c < 2; ++c) {
            int ho = (jt * 16 + lr) * 72 + c * 32 + lg * 8;
            f16x8 hh = ldf(sm, EA_HI + ho), hl = ldf(sm, EA_LO + ho);
            acc = MFMA16(wF2H[c], hh, acc);
            acc = MFMA16(wF2H[c], hl, acc);
            acc = MFMA16(wF2L[c], hh, acc);
        }
        int j = jt * 16 + lr;
        *(float4*)&out_value[(size_t)b * 512 + j * 16 + lg * 4] =
            make_float4(acc[0], acc[1], acc[2], acc[3]);
    }
}

extern "C" void kernel_launch(void* const* d_in, const int* in_sizes, int n_in,
                              void* d_out, int out_size, void* d_ws, size_t ws_size,
                              hipStream_t stream) {
    const float* states   = (const float*)d_in[0];
    const float* policies = (const float*)d_in[1];
    const float* actions  = (const float*)d_in[2];
    const float* W_obs    = (const float*)d_in[3];
    const float* b_obs    = (const float*)d_in[4];
    const float* W_oa     = (const float*)d_in[5];
    const float* b_oa     = (const float*)d_in[6];
    const float* W_key    = (const float*)d_in[7];
    const float* W_query  = (const float*)d_in[8];
    const float* W_av     = (const float*)d_in[9];
    const float* W_f1     = (const float*)d_in[10];
    const float* W_f2     = (const float*)d_in[11];

    float* out_value  = (float*)d_out;                 // [512,32,16]
    float* out_weight = (float*)d_out + 512 * 32 * 16; // [512,32,32]

    critic_mfma<<<512, 256, 0, stream>>>(states, policies, actions, b_obs, b_oa,
                                         W_obs, W_oa, W_key, W_query, W_av, W_f1, W_f2,
                                         out_value, out_weight);
}

// Round 13
// 19.076 us; speedup vs baseline: 1.2306x; 1.2306x over previous
//
#include <hip/hip_runtime.h>

typedef _Float16 f16;
typedef _Float16 f16x8 __attribute__((ext_vector_type(8)));
typedef float f32x4 __attribute__((ext_vector_type(4)));

#define MFMA16(a, b, c) __builtin_amdgcn_mfma_f32_16x16x32_f16((a), (b), (c), 0, 0, 0)

// ---------------- LDS (u16 units) ----------------
#define XS_HI  0        // states split [32][136]
#define XS_LO  4352
#define E_HI   8704     // E [32][72] -> NF reuse
#define E_LO   11008
#define EA_HI  13312    // EA -> H reuse
#define EA_LO  15616
#define EP_HI  17920
#define EP_LO  20224
#define KB_HI  22528    // K [32][72]
#define KB_LO  24832
#define QB_HI  27136    // Q [32][72]
#define QB_LO  29440
#define AAT_HI 31744    // AA transposed [64][40]
#define AAT_LO 34304
#define WM_HI  36864    // softmax w [32][40]
#define WM_LO  38144
#define WDIAG  39424    // float[32]
#define SMTOT  39488    // 78976 B -> 2 blocks/CU

__device__ __forceinline__ void split1(float v, ushort& h, ushort& lo) {
    f16 hf = (f16)v;
    float r = v - (float)hf;
    f16 lf = (f16)r;
    union { f16 f; ushort u; } a, b;
    a.f = hf; b.f = lf;
    h = a.u; lo = b.u;
}
__device__ __forceinline__ void split4(f32x4 v, ushort4& h, ushort4& l) {
    split1(v[0], h.x, l.x);
    split1(v[1], h.y, l.y);
    split1(v[2], h.z, l.z);
    split1(v[3], h.w, l.w);
}
__device__ __forceinline__ void mk8(float4 a, float4 b, f16x8& hi, f16x8& lo) {
    float v[8] = {a.x, a.y, a.z, a.w, b.x, b.y, b.z, b.w};
    #pragma unroll
    for (int j = 0; j < 8; ++j) {
        f16 h = (f16)v[j];
        hi[j] = h;
        lo[j] = (f16)(v[j] - (float)h);
    }
}
// raw fp32 weight fragment: 8 consecutive floats -> hi/lo f16x8
__device__ __forceinline__ void ldraw(const float* p, f16x8& h, f16x8& l) {
    float4 a = *(const float4*)p;
    float4 b = *(const float4*)(p + 4);
    mk8(a, b, h, l);
}
__device__ __forceinline__ f16x8 ldf(const ushort* sm, int off) {
    return *(const f16x8*)(sm + off);
}
__device__ __forceinline__ float fast_tanh(float x) {
    float xc = fminf(fmaxf(x, -9.0f), 9.0f);
    float e = __expf(2.0f * xc);
    return (e - 1.0f) * __builtin_amdgcn_rcpf(e + 1.0f);
}

__global__ void __launch_bounds__(256, 2)
critic_mfma(const float* __restrict__ states, const float* __restrict__ policies,
            const float* __restrict__ actions, const float* __restrict__ b_obs,
            const float* __restrict__ b_oa,
            const float* __restrict__ W_obs, const float* __restrict__ W_oa,
            const float* __restrict__ W_key, const float* __restrict__ W_query,
            const float* __restrict__ W_av,  const float* __restrict__ W_f1,
            const float* __restrict__ W_f2,
            float* __restrict__ out_value,   // [B,32,16]
            float* __restrict__ out_weight)  // [B,32,32]
{
    __shared__ ushort sm[SMTOT];
    const int b = blockIdx.x;
    const int t = threadIdx.x;
    const int wv = t >> 6, l = t & 63;
    const int lr = l & 15;        // lane row/col within 16-tile
    const int lg = l >> 4;        // k-group / output reg-quad
    const int ft = wv;            // feature tile (M dim) 0..3
    const int row = ft * 16 + lr;        // weight row this lane owns
    const int f0 = ft * 16 + lg * 4;     // output feature quad base

    // ---- issue states loads first (LDS staging depends on them) ----
    float4 sv[4];
    {
        const float4* src = (const float4*)(states + (size_t)b * 4096);
        #pragma unroll
        for (int r4 = 0; r4 < 4; ++r4) sv[r4] = src[t + r4 * 256];
    }

    // ---- phase-A weight fragments: raw fp32 -> split in-register ----
    f16x8 wObsH[4], wObsL[4], wOaH[4], wOaL[4];
    #pragma unroll
    for (int c = 0; c < 4; ++c) {
        ldraw(W_obs + row * 128 + c * 32 + lg * 8, wObsH[c], wObsL[c]);
        ldraw(W_oa + row * 144 + c * 32 + lg * 8, wOaH[c], wOaL[c]);
    }
    f16x8 wTailH, wTailL;
    {
        float4 t0 = make_float4(0.f, 0.f, 0.f, 0.f), t1 = t0;
        if (lg < 2) {
            t0 = *(const float4*)(W_oa + row * 144 + 128 + lg * 8);
            t1 = *(const float4*)(W_oa + row * 144 + 132 + lg * 8);
        }
        mk8(t0, t1, wTailH, wTailL);
    }

    // ---- act/pol tail B-fragments built in-register (k>=16 zero) ----
    f16x8 actH[2], actL[2], polH[2], polL[2];
    #pragma unroll
    for (int at = 0; at < 2; ++at) {
        float4 a0v = make_float4(0.f, 0.f, 0.f, 0.f), a1v = a0v, p0v = a0v, p1v = a0v;
        if (lg < 2) {
            size_t base = (size_t)b * 512 + (at * 16 + lr) * 16 + lg * 8;
            a0v = *(const float4*)(actions + base);
            a1v = *(const float4*)(actions + base + 4);
            p0v = *(const float4*)(policies + base);
            p1v = *(const float4*)(policies + base + 4);
        }
        mk8(a0v, a1v, actH[at], actL[at]);
        mk8(p0v, p1v, polH[at], polL[at]);
    }

    // ---- stage states split hi/lo into LDS ----
    #pragma unroll
    for (int r4 = 0; r4 < 4; ++r4) {
        int e4 = t + r4 * 256, srow = e4 >> 5, k0 = (e4 & 31) * 4;
        ushort4 h, lo;
        split1(sv[r4].x, h.x, lo.x);
        split1(sv[r4].y, h.y, lo.y);
        split1(sv[r4].z, h.z, lo.z);
        split1(sv[r4].w, h.w, lo.w);
        *(ushort4*)(sm + XS_HI + srow * 136 + k0) = h;
        *(ushort4*)(sm + XS_LO + srow * 136 + k0) = lo;
    }
    __syncthreads();

    const f32x4 Z = {0.f, 0.f, 0.f, 0.f};

    // ================= phase A: E = relu(S@WobsT+b); EA/EP = relu(S@WoaT + tail + b) =================
    f32x4 accE[2] = {Z, Z}, accP[2] = {Z, Z};
    __builtin_amdgcn_s_setprio(1);
    #pragma unroll
    for (int c = 0; c < 4; ++c) {
        #pragma unroll
        for (int at = 0; at < 2; ++at) {
            int ao = (at * 16 + lr) * 136 + c * 32 + lg * 8;
            f16x8 xh = ldf(sm, XS_HI + ao), xl = ldf(sm, XS_LO + ao);
            accE[at] = MFMA16(wObsH[c], xh, accE[at]);
            accE[at] = MFMA16(wObsH[c], xl, accE[at]);
            accE[at] = MFMA16(wObsL[c], xh, accE[at]);
            accP[at] = MFMA16(wOaH[c], xh, accP[at]);
            accP[at] = MFMA16(wOaH[c], xl, accP[at]);
            accP[at] = MFMA16(wOaL[c], xh, accP[at]);
        }
    }
    f32x4 accEA[2], accEP[2];
    #pragma unroll
    for (int at = 0; at < 2; ++at) {
        accEA[at] = accP[at]; accEP[at] = accP[at];
        accEA[at] = MFMA16(wTailH, actH[at], accEA[at]);
        accEA[at] = MFMA16(wTailH, actL[at], accEA[at]);
        accEA[at] = MFMA16(wTailL, actH[at], accEA[at]);
        accEP[at] = MFMA16(wTailH, polH[at], accEP[at]);
        accEP[at] = MFMA16(wTailH, polL[at], accEP[at]);
        accEP[at] = MFMA16(wTailL, polH[at], accEP[at]);
    }
    __builtin_amdgcn_s_setprio(0);

    // prefetch phase-BC weights while A finishes (raw fp32, split in-register)
    f16x8 wKH[2], wKL[2], wQH[2], wQL[2], wVH[2], wVL[2];
    #pragma unroll
    for (int c = 0; c < 2; ++c) {
        ldraw(W_key + row * 64 + c * 32 + lg * 8, wKH[c], wKL[c]);
        ldraw(W_query + row * 64 + c * 32 + lg * 8, wQH[c], wQL[c]);
        ldraw(W_av + row * 64 + c * 32 + lg * 8, wVH[c], wVL[c]);
    }

    {
        float4 bo = *(const float4*)&b_obs[f0];
        float4 ba = *(const float4*)&b_oa[f0];
        #pragma unroll
        for (int at = 0; at < 2; ++at) {
            int agent = at * 16 + lr;
            f32x4 e, ea, ep;
            e[0] = fmaxf(accE[at][0] + bo.x, 0.f);  e[1] = fmaxf(accE[at][1] + bo.y, 0.f);
            e[2] = fmaxf(accE[at][2] + bo.z, 0.f);  e[3] = fmaxf(accE[at][3] + bo.w, 0.f);
            ea[0] = fmaxf(accEA[at][0] + ba.x, 0.f); ea[1] = fmaxf(accEA[at][1] + ba.y, 0.f);
            ea[2] = fmaxf(accEA[at][2] + ba.z, 0.f); ea[3] = fmaxf(accEA[at][3] + ba.w, 0.f);
            ep[0] = fmaxf(accEP[at][0] + ba.x, 0.f); ep[1] = fmaxf(accEP[at][1] + ba.y, 0.f);
            ep[2] = fmaxf(accEP[at][2] + ba.z, 0.f); ep[3] = fmaxf(accEP[at][3] + ba.w, 0.f);
            ushort4 h, lo;
            split4(e, h, lo);
            *(ushort4*)(sm + E_HI + agent * 72 + f0) = h;
            *(ushort4*)(sm + E_LO + agent * 72 + f0) = lo;
            split4(ea, h, lo);
            *(ushort4*)(sm + EA_HI + agent * 72 + f0) = h;
            *(ushort4*)(sm + EA_LO + agent * 72 + f0) = lo;
            split4(ep, h, lo);
            *(ushort4*)(sm + EP_HI + agent * 72 + f0) = h;
            *(ushort4*)(sm + EP_LO + agent * 72 + f0) = lo;
        }
    }
    __syncthreads();

    // ================= phase BC: K=E@WkT, Q=E@WqT, AA/AP=tanh(EA/EP@WavT) =================
    f32x4 dDiff[2];
    {
        f32x4 aK[2] = {Z, Z}, aQ[2] = {Z, Z}, aA[2] = {Z, Z}, aP[2] = {Z, Z};
        __builtin_amdgcn_s_setprio(1);
        #pragma unroll
        for (int c = 0; c < 2; ++c) {
            #pragma unroll
            for (int at = 0; at < 2; ++at) {
                int ao = (at * 16 + lr) * 72 + c * 32 + lg * 8;
                f16x8 eh = ldf(sm, E_HI + ao),  el = ldf(sm, E_LO + ao);
                f16x8 xh = ldf(sm, EA_HI + ao), xl = ldf(sm, EA_LO + ao);
                f16x8 yh = ldf(sm, EP_HI + ao), yl = ldf(sm, EP_LO + ao);
                aK[at] = MFMA16(wKH[c], eh, aK[at]);
                aK[at] = MFMA16(wKH[c], el, aK[at]);
                aK[at] = MFMA16(wKL[c], eh, aK[at]);
                aQ[at] = MFMA16(wQH[c], eh, aQ[at]);
                aQ[at] = MFMA16(wQH[c], el, aQ[at]);
                aQ[at] = MFMA16(wQL[c], eh, aQ[at]);
                aA[at] = MFMA16(wVH[c], xh, aA[at]);
                aA[at] = MFMA16(wVH[c], xl, aA[at]);
                aA[at] = MFMA16(wVL[c], xh, aA[at]);
                aP[at] = MFMA16(wVH[c], yh, aP[at]);
                aP[at] = MFMA16(wVH[c], yl, aP[at]);
                aP[at] = MFMA16(wVL[c], yh, aP[at]);
            }
        }
        __builtin_amdgcn_s_setprio(0);
        #pragma unroll
        for (int at = 0; at < 2; ++at) {
            int agent = at * 16 + lr;
            ushort4 h, lo;
            split4(aK[at], h, lo);
            *(ushort4*)(sm + KB_HI + agent * 72 + f0) = h;
            *(ushort4*)(sm + KB_LO + agent * 72 + f0) = lo;
            split4(aQ[at], h, lo);
            *(ushort4*)(sm + QB_HI + agent * 72 + f0) = h;
            *(ushort4*)(sm + QB_LO + agent * 72 + f0) = lo;
            f32x4 ta, tp;
            #pragma unroll
            for (int r = 0; r < 4; ++r) {
                ta[r] = fast_tanh(aA[at][r]);
                tp[r] = fast_tanh(aP[at][r]);
            }
            dDiff[at] = tp - ta;
            #pragma unroll
            for (int r = 0; r < 4; ++r) {      // AA transposed (phase-D A-operand)
                ushort hh, ll;
                split1(ta[r], hh, ll);
                sm[AAT_HI + (f0 + r) * 40 + agent] = hh;
                sm[AAT_LO + (f0 + r) * 40 + agent] = ll;
            }
        }
    }

    // prefetch phase-E/F weights
    f16x8 wF1H[2], wF1L[2], wF2H[2], wF2L[2];
    #pragma unroll
    for (int c = 0; c < 2; ++c)
        ldraw(W_f1 + row * 64 + c * 32 + lg * 8, wF1H[c], wF1L[c]);
    if (wv < 2) {
        #pragma unroll
        for (int c = 0; c < 2; ++c)
            ldraw(W_f2 + lr * 64 + c * 32 + lg * 8, wF2H[c], wF2L[c]);
    }
    __syncthreads();

    // ================= score + softmax (waves 0,1): w[j][i] = softmax_i(q_i.k_j/8) =================
    if (wv < 2) {
        int jt = wv;
        f16x8 kh[2], kl[2];
        #pragma unroll
        for (int c = 0; c < 2; ++c) {
            int ko = (jt * 16 + lr) * 72 + c * 32 + lg * 8;
            kh[c] = ldf(sm, KB_HI + ko);
            kl[c] = ldf(sm, KB_LO + ko);
        }
        f32x4 s[2] = {Z, Z};
        __builtin_amdgcn_s_setprio(1);
        #pragma unroll
        for (int c = 0; c < 2; ++c) {
            #pragma unroll
            for (int it = 0; it < 2; ++it) {
                int qo = (it * 16 + lr) * 72 + c * 32 + lg * 8;
                f16x8 qh = ldf(sm, QB_HI + qo), ql = ldf(sm, QB_LO + qo);
                s[it] = MFMA16(kh[c], qh, s[it]);
                s[it] = MFMA16(kh[c], ql, s[it]);
                s[it] = MFMA16(kl[c], qh, s[it]);
            }
        }
        __builtin_amdgcn_s_setprio(0);
        float* wdiag = (float*)(sm + WDIAG);
        #pragma unroll
        for (int r = 0; r < 4; ++r) {
            int j = jt * 16 + lg * 4 + r;
            float v0 = s[0][r] * 0.125f, v1 = s[1][r] * 0.125f;
            float m = fmaxf(v0, v1);
            #pragma unroll
            for (int off = 1; off < 16; off <<= 1)
                m = fmaxf(m, __shfl_xor(m, off, 16));
            float e0 = __expf(v0 - m), e1 = __expf(v1 - m);
            float su = e0 + e1;
            #pragma unroll
            for (int off = 1; off < 16; off <<= 1)
                su += __shfl_xor(su, off, 16);
            float inv = 1.0f / su;
            e0 *= inv; e1 *= inv;
            out_weight[(size_t)b * 1024 + j * 32 + lr] = e0;
            out_weight[(size_t)b * 1024 + j * 32 + 16 + lr] = e1;
            ushort hh, ll;
            split1(e0, hh, ll);
            sm[WM_HI + j * 40 + lr] = hh;
            sm[WM_LO + j * 40 + lr] = ll;
            split1(e1, hh, ll);
            sm[WM_HI + j * 40 + 16 + lr] = hh;
            sm[WM_LO + j * 40 + 16 + lr] = ll;
            if (lr == lg * 4 + r) wdiag[j] = jt ? e1 : e0;
        }
    }
    __syncthreads();

    // ================= phase D: NF[j][f] = (1/32)(sum_i w[j,i]AA[i,f] + w[j,j](AP-AA)[j,f]) =================
    {
        int fo = (ft * 16 + lr) * 40 + lg * 8;
        f16x8 ah = ldf(sm, AAT_HI + fo);
        f16x8 al = ldf(sm, AAT_LO + fo);
        const float* wdiag = (const float*)(sm + WDIAG);
        #pragma unroll
        for (int jt = 0; jt < 2; ++jt) {
            int j = jt * 16 + lr;
            f16x8 wh = ldf(sm, WM_HI + j * 40 + lg * 8);
            f16x8 wl = ldf(sm, WM_LO + j * 40 + lg * 8);
            f32x4 acc = Z;
            acc = MFMA16(ah, wh, acc);
            acc = MFMA16(ah, wl, acc);
            acc = MFMA16(al, wh, acc);
            float wd = wdiag[j];
            f32x4 nf;
            #pragma unroll
            for (int r = 0; r < 4; ++r)
                nf[r] = (acc[r] + wd * dDiff[jt][r]) * 0.03125f;
            ushort4 h, lo;
            split4(nf, h, lo);
            *(ushort4*)(sm + E_HI + j * 72 + f0) = h;   // NF overwrites E (dead)
            *(ushort4*)(sm + E_LO + j * 72 + f0) = lo;
        }
    }
    __syncthreads();

    // ================= phase E: H = leaky_relu(NF @ Wf1T) =================
    {
        f32x4 hA[2] = {Z, Z};
        __builtin_amdgcn_s_setprio(1);
        #pragma unroll
        for (int c = 0; c < 2; ++c) {
            #pragma unroll
            for (int jt = 0; jt < 2; ++jt) {
                int bo2 = (jt * 16 + lr) * 72 + c * 32 + lg * 8;
                f16x8 nh_ = ldf(sm, E_HI + bo2), nl_ = ldf(sm, E_LO + bo2);
                hA[jt] = MFMA16(wF1H[c], nh_, hA[jt]);
                hA[jt] = MFMA16(wF1H[c], nl_, hA[jt]);
                hA[jt] = MFMA16(wF1L[c], nh_, hA[jt]);
            }
        }
        __builtin_amdgcn_s_setprio(0);
        #pragma unroll
        for (int jt = 0; jt < 2; ++jt) {
            int j = jt * 16 + lr;
            f32x4 hv;
            #pragma unroll
            for (int r = 0; r < 4; ++r)
                hv[r] = fmaxf(hA[jt][r], 0.01f * hA[jt][r]);
            ushort4 h, lo;
            split4(hv, h, lo);
            *(ushort4*)(sm + EA_HI + j * 72 + f0) = h;  // H overwrites EA (dead)
            *(ushort4*)(sm + EA_LO + j * 72 + f0) = lo;
        }
    }
    __syncthreads();

    // ================= phase F (waves 0,1): value = H @ Wf2T =================
    if (wv < 2) {
        int jt = wv;
        f32x4 acc = Z;
        #pragma unroll
        for (int c = 0; c < 2; ++c) {
            int ho = (jt * 16 + lr) * 72 + c * 32 + lg * 8;
            f16x8 hh = ldf(sm, EA_HI + ho), hl = ldf(sm, EA_LO + ho);
            acc = MFMA16(wF2H[c], hh, acc);
            acc = MFMA16(wF2H[c], hl, acc);
            acc = MFMA16(wF2L[c], hh, acc);
        }
        int j = jt * 16 + lr;
        *(float4*)&out_value[(size_t)b * 512 + j * 16 + lg * 4] =
            make_float4(acc[0], acc[1], acc[2], acc[3]);
    }
}

extern "C" void kernel_launch(void* const* d_in, const int* in_sizes, int n_in,
                              void* d_out, int out_size, void* d_ws, size_t ws_size,
                              hipStream_t stream) {
    const float* states   = (const float*)d_in[0];
    const float* policies = (const float*)d_in[1];
    const float* actions  = (const float*)d_in[2];
    const float* W_obs    = (const float*)d_in[3];
    const float* b_obs    = (const float*)d_in[4];
    const float* W_oa     = (const float*)d_in[5];
    const float* b_oa     = (const float*)d_in[6];
    const float* W_key    = (const float*)d_in[7];
    const float* W_query  = (const float*)d_in[8];
    const float* W_av     = (const float*)d_in[9];
    const float* W_f1     = (const float*)d_in[10];
    const float* W_f2     = (const float*)d_in[11];

    float* out_value  = (float*)d_out;                 // [512,32,16]
    float* out_weight = (float*)d_out + 512 * 32 * 16; // [512,32,32]

    critic_mfma<<<512, 256, 0, stream>>>(states, policies, actions, b_obs, b_oa,
                                         W_obs, W_oa, W_key, W_query, W_av, W_f1, W_f2,
                                         out_value, out_weight);
}